// Round 16
// baseline (1427.183 us; speedup 1.0000x reference)
//
#include <hip/hip_runtime.h>
#include <hip/hip_bf16.h>
#include <hip/hip_fp8.h>
#include <math.h>

// ---------------------------------------------------------------------------
// PicanetG: Renet (2x BiLSTM, HID=256) + 1x1 conv(484) + softmax + attention.
// Round 15: renet_fused take 2 — R13's fused gate-GEMM+recurrence (proven
//   correct) with the spill fixed:
//   (1) amdgpu_waves_per_eu(4,4): exactly 4 waves/SIMD -> 128-VGPR budget
//       (R13: compiler squeezed to 64 regs -> 1.6 GB scratch, 665us).
//   (2) gate GEMM in 4 q-passes (acc 8 regs), int B-offsets.
//   Final GEMM keeps R15 dbuf; conv_sm / xtrans / gather unchanged.
//
// ws (float units), REQ = 33554432 fl = 134,217,728 B:
//   xt    @ 0         bf16 [32768][512] (32 MiB); later Pch bf16 [4096][512]
//   V     @ 8388608   bf16 [32768][512] (32 MiB)
//   HF    @ 16777216  bf16 [32768][512] (32 MiB)
//   kernT @ 25165824  bf16 [8][4096][512] (32 MiB)
// d_out tail scratch (fl offset): wt bf16 @ +8388608 ([vf;vb;hf;hb][512k]),
//   cw2b @ +9437184, cb2 @ +9568256, wq fp8 @ +9568768 (consumed pre-final).
// ---------------------------------------------------------------------------

typedef __hip_bfloat16 bf16;
typedef short short8 __attribute__((ext_vector_type(8)));
typedef float f4 __attribute__((ext_vector_type(4)));
typedef int int4v __attribute__((ext_vector_type(4)));
typedef int int8v __attribute__((ext_vector_type(8)));

#define SCL8 0x7F7F7F7F   // e8m0 = 127 in every byte -> scale 1.0

__device__ __forceinline__ unsigned short bfbits(float f) {
    bf16 h = __float2bfloat16(f);
    return *reinterpret_cast<unsigned short*>(&h);
}
__device__ __forceinline__ float bf2f(unsigned short u) {
    union { unsigned int i; float f; } x; x.i = ((unsigned int)u) << 16; return x.f;
}
__device__ __forceinline__ unsigned char f2fp8(float f) {
    __hip_fp8_e4m3 q(f);
    return *reinterpret_cast<unsigned char*>(&q);
}
__device__ __forceinline__ float sigm2(float x) {
    return __builtin_amdgcn_rcpf(1.0f + __builtin_amdgcn_exp2f(x * -1.44269504f));
}
__device__ __forceinline__ float tanh2(float x) {
    return 1.0f - 2.0f * __builtin_amdgcn_rcpf(1.0f + __builtin_amdgcn_exp2f(x * 2.88539008f));
}

// async global->LDS, 16B/lane; lds dest = wave-uniform base + lane*16.
#define GLD16(g, s) __builtin_amdgcn_global_load_lds(                          \
    (const __attribute__((address_space(1))) void*)(g),                        \
    (__attribute__((address_space(3))) void*)(s), 16, 0, 0)

// barrier that does NOT drain vmcnt: LDS ordering only.
#define LGKM_BARRIER() do {                                                    \
    asm volatile("s_waitcnt lgkmcnt(0)" ::: "memory");                         \
    __builtin_amdgcn_s_barrier();                                              \
} while (0)

// ---------------------------------------------------------------------------
// prep_weights: wt bf16 [4][1024 g][512 k] ([vf;vb;hf;hb]); cw2b [512][512];
//               cb2 [512]; wq e4m3 [4][1024 g][256 k].
// ---------------------------------------------------------------------------
__global__ __launch_bounds__(256)
void prep_weights(const float* __restrict__ w0, const float* __restrict__ w1,
                  const float* __restrict__ w2, const float* __restrict__ w3,
                  const float* __restrict__ cw, const float* __restrict__ cb,
                  const float* __restrict__ u0, const float* __restrict__ u1,
                  const float* __restrict__ u2, const float* __restrict__ u3,
                  bf16* __restrict__ wt, bf16* __restrict__ cw2b,
                  float* __restrict__ cb2, unsigned char* __restrict__ wq)
{
    int idx = blockIdx.x * 256 + threadIdx.x;
    if (idx < 2097152) {
        int mat = idx >> 19, rem = idx & 524287;
        const float* src = (mat == 0) ? w0 : (mat == 1) ? w1 : (mat == 2) ? w2 : w3;
        wt[idx] = __float2bfloat16(src[rem]);
    } else if (idx < 2097152 + 262144) {
        int r = idx - 2097152; int o = r >> 9, k = r & 511;
        cw2b[r] = __float2bfloat16((o < 484) ? cw[o * 512 + k] : 0.f);
    } else if (idx < 2097152 + 262144 + 512) {
        int o = idx - 2097152 - 262144;
        cb2[o] = (o < 484) ? cb[o] : 0.f;
    } else if (idx < 2097152 + 262144 + 512 + 1048576) {
        int r = idx - 2097152 - 262144 - 512;
        int mat = r >> 18, rem = r & 262143;
        const float* src = (mat == 0) ? u0 : (mat == 1) ? u1 : (mat == 2) ? u2 : u3;
        wq[r] = f2fp8(src[rem]);
    }
}

// ---------------------------------------------------------------------------
// xtrans: x [8][512][64][64] fp32 -> xt [b*4096 + h*64 + w][512 c] bf16.
// ---------------------------------------------------------------------------
__global__ __launch_bounds__(256)
void xtrans(const float* __restrict__ x, bf16* __restrict__ xt)
{
    __shared__ float T[64][65];
    const int tid = threadIdx.x;
    const int bid = blockIdx.x;
    const int b = bid >> 9, h = (bid >> 3) & 63, ct = bid & 7;
    const int c0 = ct << 6;
    const float* xp = x + ((long)(b * 512 + c0) * 64 + h) * 64;
    const int wv = tid >> 6, wl = tid & 63;
    #pragma unroll
    for (int r = 0; r < 16; ++r) {
        int ci = wv + (r << 2);
        T[ci][wl] = xp[(long)ci * 4096 + wl];
    }
    __syncthreads();
    const int wr = tid >> 2, cj = (tid & 3) << 4;
    bf16* op = xt + ((long)(b * 4096 + h * 64 + wr) * 512) + c0 + cj;
    short8 v0, v1;
    #pragma unroll
    for (int i = 0; i < 8; ++i) v0[i] = (short)bfbits(T[cj + i][wr]);
    #pragma unroll
    for (int i = 0; i < 8; ++i) v1[i] = (short)bfbits(T[cj + 8 + i][wr]);
    *(short8*)op = v0;
    *(short8*)(op + 8) = v1;
}

// ---------------------------------------------------------------------------
// renet_fused: gate GEMM + LSTM recurrence, one dir + 4 seqs per WG.
// 256 WGs (dir = bid>>7), 1024 thr = 16 waves, 1 WG/CU (LDS 82 KB).
// waves_per_eu(4,4) -> exactly 4 waves/SIMD -> 128-VGPR budget (no spill).
// Per chunk (8 t): A-tile [32 rows][512 k] staged swizzled; G-chunk = A x
// Wih^T + bias via bf16 MFMA in 4 q-passes (B streamed from L2, acc 2xf4);
// Gch LDS [seq][tt][256 j][4 q] (wave-private in j); then 8 MX-fp8
// recurrence steps (G from LDS; spread-row: lane owns cell (seq=lg,
// hid=wv*16+lm); h fp8 in hbuf). Out h bf16 swapped-on-write.
// ---------------------------------------------------------------------------
__global__ __attribute__((amdgpu_waves_per_eu(4, 4))) __launch_bounds__(1024)
void renet_fused(const bf16* __restrict__ A, const bf16* __restrict__ Wih,
                 const float* __restrict__ biasf, const float* __restrict__ biasb,
                 const unsigned char* __restrict__ Wqf,
                 const unsigned char* __restrict__ Wqb,
                 bf16* __restrict__ Out)
{
    __shared__ alignas(16) char Atile[2][32768];      // [buf][32 rows][1024 B]
    __shared__ unsigned short Gch[4][8][256][4];      // 16 KB
    __shared__ unsigned char hbuf[2][4][256];         // 2 KB fp8 h

    const int tid = threadIdx.x;
    const int wv = tid >> 6, l = tid & 63;
    const int lm = l & 15, lg = l >> 4;
    const int j_c = wv * 16 + lm;
    const int s_a = lm >> 2;

    const int dir  = blockIdx.x >> 7;
    const int sblk = blockIdx.x & 127;
    const int s0 = sblk << 2;
    const unsigned char* WQ = dir ? Wqb : Wqf;
    const float* bs = dir ? biasb : biasf;
    const bf16* Wd = Wih + ((long)dir << 10) * 512;

    // Whh fp8 MX B-frags: col g = q*256 + j_c, kappa = kt*128 + lg*32 + j
    int8v wfrag[4][2];
    #pragma unroll
    for (int q = 0; q < 4; ++q) {
        const unsigned char* wr = WQ + (long)((q << 8) + j_c) * 256 + (lg << 5);
        #pragma unroll
        for (int kt = 0; kt < 2; ++kt) {
            int4v lo = *(const int4v*)(wr + kt * 128);
            int4v hi = *(const int4v*)(wr + kt * 128 + 16);
            int8v w;
            w[0] = lo[0]; w[1] = lo[1]; w[2] = lo[2]; w[3] = lo[3];
            w[4] = hi[0]; w[5] = hi[1]; w[6] = hi[2]; w[7] = hi[3];
            wfrag[q][kt] = w;
        }
    }

    float bv[4];
    #pragma unroll
    for (int q = 0; q < 4; ++q) bv[q] = bs[(q << 8) + j_c];

    if (tid < 256) ((unsigned long*)hbuf)[tid] = 0ul;   // zero h state

    float cst = 0.f;
    const long ob0 = ((long)((s0 >> 6) * 4096 + (s0 & 63) + lg)) * 512
                   + (dir << 8) + j_c;
    unsigned short* Ou = (unsigned short*)Out;

    // Wih per-lane element offsets (int: max ~1M elements, fits)
    int wboff[4];
    #pragma unroll
    for (int q = 0; q < 4; ++q)
        wboff[q] = ((q << 8) + j_c) * 512 + (lg << 3);

    const int swz0 = (lm & 7) << 4;   // A-frag swizzle (rows lm, 16+lm alias)

    // ---- prologue: stage chunk 0 into buf 0 ----
    {
        const int tb = dir ? 56 : 0;
        #pragma unroll
        for (int sw = 0; sw < 2; ++sw) {
            const int r = sw * 16 + wv;
            const int n = (s0 + (r >> 3)) * 64 + tb + (r & 7);
            const int soff = (l * 16) ^ ((r & 7) << 4);
            GLD16(A + (long)n * 512 + (soff >> 1), &Atile[0][r << 10]);
        }
    }
    asm volatile("s_waitcnt vmcnt(0)" ::: "memory");
    __builtin_amdgcn_s_barrier();

    int buf = 0;
    for (int c = 0; c < 8; ++c) {
        // ---- stage next chunk's A-tile (lands during GEMM+recurrence) ----
        if (c < 7) {
            const int tb = dir ? 56 - 8 * (c + 1) : 8 * (c + 1);
            #pragma unroll
            for (int sw = 0; sw < 2; ++sw) {
                const int r = sw * 16 + wv;
                const int n = (s0 + (r >> 3)) * 64 + tb + (r & 7);
                const int soff = (l * 16) ^ ((r & 7) << 4);
                GLD16(A + (long)n * 512 + (soff >> 1), &Atile[buf ^ 1][r << 10]);
            }
        }

        // ---- gate GEMM: G-chunk = A x Wih^T + bias, 4 q-passes (low regs) --
        const char* Ab = Atile[buf];
        #pragma unroll
        for (int qp = 0; qp < 4; ++qp) {
            f4 acc0 = (f4){0.f, 0.f, 0.f, 0.f};
            f4 acc1 = (f4){0.f, 0.f, 0.f, 0.f};
            #pragma unroll
            for (int ks = 0; ks < 16; ++ks) {
                const int ko = ((ks << 6) + (lg << 4)) ^ swz0;
                short8 a0 = *(const short8*)(Ab + (lm << 10) + ko);
                short8 a1 = *(const short8*)(Ab + ((16 + lm) << 10) + ko);
                short8 b0 = *(const short8*)(Wd + wboff[qp] + (ks << 5));
                acc0 = __builtin_amdgcn_mfma_f32_16x16x32_bf16(a0, b0, acc0, 0, 0, 0);
                acc1 = __builtin_amdgcn_mfma_f32_16x16x32_bf16(a1, b0, acc1, 0, 0, 0);
            }
            #pragma unroll
            for (int r = 0; r < 4; ++r) {
                const int row0 = lg * 4 + r;
                Gch[row0 >> 3][row0 & 7][j_c][qp] = bfbits(acc0[r] + bv[qp]);
                const int row1 = 16 + row0;
                Gch[row1 >> 3][row1 & 7][j_c][qp] = bfbits(acc1[r] + bv[qp]);
            }
        }
        asm volatile("s_waitcnt lgkmcnt(0)" ::: "memory");
        __builtin_amdgcn_s_barrier();

        // ---- 8 recurrence steps, G from LDS ----
        #pragma unroll
        for (int i = 0; i < 8; ++i) {
            const int sp = (c << 3) + i;
            const int t_ = dir ? 63 - sp : sp;
            const int toff = dir ? 7 - i : i;
            const int RB = i & 1, WB = 1 - RB;   // sp parity == i parity

            int8v af0, af1;
            {
                const unsigned char* hb = &hbuf[RB][s_a][0];
                const int c0i = ((lg << 5) + (s_a << 5)) & 255;
                const int c1i = (128 + (lg << 5) + (s_a << 5)) & 255;
                int4v a0 = *(const int4v*)(hb + c0i);
                int4v a1 = *(const int4v*)(hb + c0i + 16);
                int4v b0 = *(const int4v*)(hb + c1i);
                int4v b1 = *(const int4v*)(hb + c1i + 16);
                af0[0]=a0[0]; af0[1]=a0[1]; af0[2]=a0[2]; af0[3]=a0[3];
                af0[4]=a1[0]; af0[5]=a1[1]; af0[6]=a1[2]; af0[7]=a1[3];
                af1[0]=b0[0]; af1[1]=b0[1]; af1[2]=b0[2]; af1[3]=b0[3];
                af1[4]=b1[0]; af1[5]=b1[1]; af1[6]=b1[2]; af1[7]=b1[3];
            }
            ushort4 Gr = *(const ushort4*)&Gch[lg][toff][j_c][0];
            f4 ac0 = {0.f,0.f,0.f,0.f}, ac1 = {0.f,0.f,0.f,0.f};
            f4 ac2 = {0.f,0.f,0.f,0.f}, ac3 = {0.f,0.f,0.f,0.f};
            ac0[0] = bf2f(Gr.x); ac1[0] = bf2f(Gr.y);
            ac2[0] = bf2f(Gr.z); ac3[0] = bf2f(Gr.w);

            ac0 = __builtin_amdgcn_mfma_scale_f32_16x16x128_f8f6f4(af0, wfrag[0][0], ac0, 0, 0, 0, SCL8, 0, SCL8);
            ac1 = __builtin_amdgcn_mfma_scale_f32_16x16x128_f8f6f4(af0, wfrag[1][0], ac1, 0, 0, 0, SCL8, 0, SCL8);
            ac2 = __builtin_amdgcn_mfma_scale_f32_16x16x128_f8f6f4(af0, wfrag[2][0], ac2, 0, 0, 0, SCL8, 0, SCL8);
            ac3 = __builtin_amdgcn_mfma_scale_f32_16x16x128_f8f6f4(af0, wfrag[3][0], ac3, 0, 0, 0, SCL8, 0, SCL8);
            ac0 = __builtin_amdgcn_mfma_scale_f32_16x16x128_f8f6f4(af1, wfrag[0][1], ac0, 0, 0, 0, SCL8, 0, SCL8);
            ac1 = __builtin_amdgcn_mfma_scale_f32_16x16x128_f8f6f4(af1, wfrag[1][1], ac1, 0, 0, 0, SCL8, 0, SCL8);
            ac2 = __builtin_amdgcn_mfma_scale_f32_16x16x128_f8f6f4(af1, wfrag[2][1], ac2, 0, 0, 0, SCL8, 0, SCL8);
            ac3 = __builtin_amdgcn_mfma_scale_f32_16x16x128_f8f6f4(af1, wfrag[3][1], ac3, 0, 0, 0, SCL8, 0, SCL8);

            {
                float ii = sigm2(ac0[0]);
                float ff = sigm2(ac1[0]);
                float gc = tanh2(ac2[0]);
                float oo = sigm2(ac3[0]);
                float cc = ff * cst + ii * gc;
                cst = cc;
                float h_ = oo * tanh2(cc);
                hbuf[WB][lg][(j_c + (lg << 5)) & 255] = f2fp8(h_);
                Ou[ob0 + (long)t_ * 32768] = bfbits(h_);
            }
            LGKM_BARRIER();
        }

        // chunk boundary: drain A(c+1) staging before its ds_reads
        asm volatile("s_waitcnt vmcnt(0)" ::: "memory");
        __builtin_amdgcn_s_barrier();
        buf ^= 1;
    }
}

// ---------------------------------------------------------------------------
// gemm_lds: dbuf MFMA GEMM (MODE 2 = final attention GEMM). R15 version.
// ---------------------------------------------------------------------------
template<int MODE>
__global__ __launch_bounds__(256)
void gemm_lds(const bf16* __restrict__ A, const bf16* __restrict__ W,
              void* __restrict__ outf)
{
    __shared__ alignas(16) char Abuf[2][16384];
    __shared__ alignas(16) char Bbuf[2][16384];
    const int tid = threadIdx.x;
    const int wv = tid >> 6, l = tid & 63;
    const int lm = l & 15, lg = l >> 4;
    const int wm = wv >> 1, wn = wv & 1;

    const int nx = gridDim.x;
    int bid = blockIdx.y * nx + blockIdx.x;
    const int cpx = (nx * gridDim.y) >> 3;
    bid = (bid & 7) * cpx + (bid >> 3);
    const int bx = bid % nx;
    const int n0 = (bid / nx) << 7;

    const int g0 = bx << 7;
    const bf16* Wg = W + (long)(n0 >> 9) * 2097152;

    f4 acc[4][4];
    #pragma unroll
    for (int mf = 0; mf < 4; ++mf)
        #pragma unroll
        for (int nf = 0; nf < 4; ++nf)
            acc[mf][nf] = (f4){0.f, 0.f, 0.f, 0.f};

    auto stage = [&](int kt, int pb) {
        const int k0 = kt << 6;
        #pragma unroll
        for (int i = 0; i < 4; ++i) {
            const int seg = (wv << 2) + i;
            const int L = (seg << 10) + l * 16;
            const int row = L >> 7;
            const int off = (L & 127) ^ ((row & 7) << 4);
            GLD16(A + (long)(n0 + row) * 512 + k0 + (off >> 1), &Abuf[pb][seg << 10]);
        }
        #pragma unroll
        for (int i = 0; i < 4; ++i) {
            const int seg = (wv << 2) + i;
            const int L = (seg << 10) + l * 16;
            const int row = L >> 7;
            const int off = (L & 127) ^ ((row & 7) << 4);
            GLD16(Wg + (long)(g0 + row) * 512 + k0 + (off >> 1), &Bbuf[pb][seg << 10]);
        }
    };

    stage(0, 0);
    asm volatile("s_waitcnt vmcnt(0)" ::: "memory");
    __builtin_amdgcn_s_barrier();

    int cur = 0;
    for (int kt = 0; kt < 8; ++kt) {
        if (kt < 7) stage(kt + 1, cur ^ 1);

        #pragma unroll
        for (int kk = 0; kk < 2; ++kk) {
            short8 af[4], bq[4];
            #pragma unroll
            for (int mf = 0; mf < 4; ++mf) {
                const int row = wm * 64 + mf * 16 + lm;
                const int ad = (row << 7) + ((((kk << 6) + (lg << 4))) ^ ((row & 7) << 4));
                af[mf] = *(const short8*)&Abuf[cur][ad];
            }
            #pragma unroll
            for (int nf = 0; nf < 4; ++nf) {
                const int row = wn * 64 + nf * 16 + lm;
                const int ad = (row << 7) + ((((kk << 6) + (lg << 4))) ^ ((row & 7) << 4));
                bq[nf] = *(const short8*)&Bbuf[cur][ad];
            }
            #pragma unroll
            for (int mf = 0; mf < 4; ++mf)
                #pragma unroll
                for (int nf = 0; nf < 4; ++nf)
                    acc[mf][nf] = __builtin_amdgcn_mfma_f32_16x16x32_bf16(af[mf], bq[nf], acc[mf][nf], 0, 0, 0);
        }

        asm volatile("s_waitcnt vmcnt(0)" ::: "memory");
        __builtin_amdgcn_s_barrier();
        cur ^= 1;
    }

    float* o = (float*)outf;
    #pragma unroll
    for (int mf = 0; mf < 4; ++mf)
        #pragma unroll
        for (int r = 0; r < 4; ++r) {
            const int n = n0 + wm * 64 + mf * 16 + lg * 4 + r;
            #pragma unroll
            for (int nf = 0; nf < 4; ++nf)
                o[(long)n * 4096 + g0 + wn * 64 + nf * 16 + lm] = acc[mf][nf][r];
        }
}

// ---------------------------------------------------------------------------
// conv_sm: fused 1x1 conv + bias + row-softmax(o<484) -> kernT bf16 [n][512].
// (R12, unchanged.)
// ---------------------------------------------------------------------------
__global__ __launch_bounds__(512)
void conv_sm(const bf16* __restrict__ A, const bf16* __restrict__ W,
             const float* __restrict__ bias, bf16* __restrict__ KT)
{
    __shared__ alignas(16) char SMEM[83968];
    char* Ab = SMEM;
    char* Bb = SMEM + 16384;
    float (*red)[4] = (float(*)[4])(SMEM + 81920);

    const int tid = threadIdx.x;
    const int wv = tid >> 6, l = tid & 63;
    const int lm = l & 15, lg = l >> 4;
    const int wm = wv >> 2, wn = wv & 3;
    const int n0 = blockIdx.x << 7;

    f4 acc[4][8];
    #pragma unroll
    for (int mf = 0; mf < 4; ++mf)
        #pragma unroll
        for (int nf = 0; nf < 8; ++nf)
            acc[mf][nf] = (f4){0.f, 0.f, 0.f, 0.f};

    for (int kt = 0; kt < 8; ++kt) {
        const int k0 = kt << 6;
        #pragma unroll
        for (int i = 0; i < 2; ++i) {
            const int L = (i << 13) + tid * 16;
            const int row = L >> 7;
            const int off = (L & 127) ^ ((row & 7) << 4);
            GLD16(A + (long)(n0 + row) * 512 + k0 + (off >> 1),
                  Ab + (i << 13) + (wv << 10));
        }
        #pragma unroll
        for (int j = 0; j < 8; ++j) {
            const int L = (j << 13) + tid * 16;
            const int row = L >> 7;
            const int off = (L & 127) ^ ((row & 7) << 4);
            GLD16(W + (long)row * 512 + k0 + (off >> 1),
                  Bb + (j << 13) + (wv << 10));
        }
        __syncthreads();
        #pragma unroll
        for (int kk = 0; kk < 2; ++kk) {
            short8 af[4], bq[8];
            #pragma unroll
            for (int mf = 0; mf < 4; ++mf) {
                const int row = wm * 64 + mf * 16 + lm;
                const int ad = (row << 7) + ((((kk << 6) + (lg << 4))) ^ ((row & 7) << 4));
                af[mf] = *(const short8*)&Ab[ad];
            }
            #pragma unroll
            for (int nf = 0; nf < 8; ++nf) {
                const int row = wn * 128 + nf * 16 + lm;
                const int ad = (row << 7) + ((((kk << 6) + (lg << 4))) ^ ((row & 7) << 4));
                bq[nf] = *(const short8*)&Bb[ad];
            }
            #pragma unroll
            for (int mf = 0; mf < 4; ++mf)
                #pragma unroll
                for (int nf = 0; nf < 8; ++nf)
                    acc[mf][nf] = __builtin_amdgcn_mfma_f32_16x16x32_bf16(af[mf], bq[nf], acc[mf][nf], 0, 0, 0);
        }
        __syncthreads();
    }

    float bv[8];
    bool alive[8];
    #pragma unroll
    for (int nf = 0; nf < 8; ++nf) {
        const int col = wn * 128 + nf * 16 + lm;
        bv[nf] = bias[col];
        alive[nf] = (col < 484);
    }

    #pragma unroll
    for (int mf = 0; mf < 4; ++mf) {
        #pragma unroll
        for (int r = 0; r < 4; ++r) {
            float m = -3.4e38f;
            #pragma unroll
            for (int nf = 0; nf < 8; ++nf) {
                float v = acc[mf][nf][r] + bv[nf];
                if (alive[nf]) m = fmaxf(m, v);
            }
            m = fmaxf(m, __shfl_xor(m, 1));
            m = fmaxf(m, __shfl_xor(m, 2));
            m = fmaxf(m, __shfl_xor(m, 4));
            m = fmaxf(m, __shfl_xor(m, 8));
            if (lm == 0) red[wm * 64 + mf * 16 + lg * 4 + r][wn] = m;
        }
    }
    __syncthreads();
    float mxv[4][4];
    #pragma unroll
    for (int mf = 0; mf < 4; ++mf)
        #pragma unroll
        for (int r = 0; r < 4; ++r) {
            const int row = wm * 64 + mf * 16 + lg * 4 + r;
            mxv[mf][r] = fmaxf(fmaxf(red[row][0], red[row][1]),
                               fmaxf(red[row][2], red[row][3]));
        }
    __syncthreads();
    #pragma unroll
    for (int mf = 0; mf < 4; ++mf) {
        #pragma unroll
        for (int r = 0; r < 4; ++r) {
            float s = 0.f;
            #pragma unroll
            for (int nf = 0; nf < 8; ++nf) {
                float v = acc[mf][nf][r] + bv[nf];
                float e = alive[nf]
                    ? __builtin_amdgcn_exp2f((v - mxv[mf][r]) * 1.44269504f) : 0.f;
                acc[mf][nf][r] = e;
                s += e;
            }
            s += __shfl_xor(s, 1);
            s += __shfl_xor(s, 2);
            s += __shfl_xor(s, 4);
            s += __shfl_xor(s, 8);
            if (lm == 0) red[wm * 64 + mf * 16 + lg * 4 + r][wn] = s;
        }
    }
    __syncthreads();
    float invv[4][4];
    #pragma unroll
    for (int mf = 0; mf < 4; ++mf)
        #pragma unroll
        for (int r = 0; r < 4; ++r) {
            const int row = wm * 64 + mf * 16 + lg * 4 + r;
            invv[mf][r] = __builtin_amdgcn_rcpf(red[row][0] + red[row][1] +
                                                red[row][2] + red[row][3]);
        }

    unsigned short* TB = (unsigned short*)Bb;
    unsigned short* KTu = (unsigned short*)KT;
    #pragma unroll
    for (int hm = 0; hm < 2; ++hm) {
        __syncthreads();
        if (wm == hm) {
            #pragma unroll
            for (int mf = 0; mf < 4; ++mf)
                #pragma unroll
                for (int r = 0; r < 4; ++r) {
                    const int rr = mf * 16 + lg * 4 + r;
                    #pragma unroll
                    for (int nf = 0; nf < 8; ++nf)
                        TB[rr * 512 + wn * 128 + nf * 16 + lm] =
                            bfbits(acc[mf][nf][r] * invv[mf][r]);
                }
        }
        __syncthreads();
        #pragma unroll
        for (int s = 0; s < 8; ++s) {
            const int L = (s << 13) + tid * 16;
            const int rr = L >> 10;
            const int cc = (L & 1023) >> 1;
            *(short8*)(KTu + (long)(n0 + hm * 64 + rr) * 512 + cc) =
                *(const short8*)((const char*)TB + L);
        }
    }
}

// ---------------------------------------------------------------------------
// gather_patch: Pch[b*512+c][o] = bf16(x[b, c, 3*(o/22), 3*(o%22)]), 0 o>=484.
// ---------------------------------------------------------------------------
__global__ __launch_bounds__(256)
void gather_patch(const float* __restrict__ x, bf16* __restrict__ Pch)
{
    int idx = blockIdx.x * 256 + threadIdx.x;
    if (idx >= 2097152) return;
    int o = idx & 511, c = (idx >> 9) & 511, b = idx >> 18;
    float v = 0.f;
    if (o < 484) {
        int i = o / 22, jj = o - i * 22;
        v = x[(long)b * 2097152 + (long)c * 4096 + i * 192 + jj * 3];
    }
    Pch[idx] = __float2bfloat16(v);
}

// ---------------------------------------------------------------------------
extern "C" void kernel_launch(void* const* d_in, const int* in_sizes, int n_in,
                              void* d_out, int out_size, void* d_ws, size_t ws_size,
                              hipStream_t stream)
{
    const float* x        = (const float*)d_in[0];
    const float* v_wih_f  = (const float*)d_in[1];
    const float* v_whh_f  = (const float*)d_in[2];
    const float* v_b_f    = (const float*)d_in[3];
    const float* v_wih_b  = (const float*)d_in[4];
    const float* v_whh_b  = (const float*)d_in[5];
    const float* v_b_b    = (const float*)d_in[6];
    const float* h_wih_f  = (const float*)d_in[7];
    const float* h_whh_f  = (const float*)d_in[8];
    const float* h_b_f    = (const float*)d_in[9];
    const float* h_wih_b  = (const float*)d_in[10];
    const float* h_whh_b  = (const float*)d_in[11];
    const float* h_b_b    = (const float*)d_in[12];
    const float* conv_w   = (const float*)d_in[13];
    const float* conv_b   = (const float*)d_in[14];

    const size_t REQ = 33554432UL * 4UL;   // 134,217,728 B
    if (ws_size < REQ) return;             // clean-fail diagnostic

    float* wsf = (float*)d_ws;
    float* out = (float*)d_out;

    // d_out tail scratch (dead before final gemm overwrites it)
    bf16*          wt   = (bf16*)(out + 8388608);
    bf16*          cw2b = (bf16*)(out + 9437184);
    float*         cb2  = out + 9568256;
    unsigned char* wq   = (unsigned char*)(out + 9568768);

    prep_weights<<<13314, 256, 0, stream>>>(v_wih_f, v_wih_b, h_wih_f, h_wih_b,
                                            conv_w, conv_b,
                                            v_whh_f, v_whh_b, h_whh_f, h_whh_b,
                                            wt, cw2b, cb2, wq);
    bf16* wt_v = wt;                 // [vf;vb] 2048 rows x 512
    bf16* wt_h = wt + 1048576;       // [hf;hb]
    unsigned char* wq_vf = wq;
    unsigned char* wq_vb = wq + 262144;
    unsigned char* wq_hf = wq + 524288;
    unsigned char* wq_hb = wq + 786432;

    bf16* xt    = (bf16*)d_ws;
    bf16* V     = (bf16*)(wsf + 8388608);
    bf16* HF    = (bf16*)(wsf + 16777216);
    bf16* kernT = (bf16*)(wsf + 25165824);
    bf16* Pch   = (bf16*)d_ws;       // aliases xt (dead after vertical pass)

    xtrans<<<4096, 256, 0, stream>>>(x, xt);
    renet_fused<<<256, 1024, 0, stream>>>(xt, wt_v, v_b_f, v_b_b, wq_vf, wq_vb, V);
    renet_fused<<<256, 1024, 0, stream>>>(V, wt_h, h_b_f, h_b_b, wq_hf, wq_hb, HF);
    conv_sm<<<256, 512, 0, stream>>>(HF, cw2b, cb2, kernT);
    gather_patch<<<8192, 256, 0, stream>>>(x, Pch);
    dim3 gF(32, 32);
    gemm_lds<2><<<gF, 256, 0, stream>>>(Pch, kernT, out);
}

// Round 17
// 404.003 us; speedup vs baseline: 3.5326x; 3.5326x over previous
//
#include <hip/hip_runtime.h>
#include <hip/hip_bf16.h>
#include <hip/hip_fp8.h>
#include <math.h>

// ---------------------------------------------------------------------------
// PicanetG: Renet (2x BiLSTM, HID=256) + 1x1 conv(484) + softmax + attention.
// Round 16: REVERT to the 410.8us split pipeline (fusion dead: compiler pins
//   16-wave WGs at 64 VGPR and spills, twice). Single change vs that build:
//   gemm_lds uses T4 counted-vmcnt 2-deep staging — pre-stage tiles 0,1;
//   per K-step wait vmcnt(8) (current tile only), never drain to 0 mid-loop;
//   stage(kt+2) after the post-MFMA barrier. Loads span two MFMA phases.
//
// FUSED ws (float units), REQ = 50331648 fl = 201,326,592 B:
//   Gf @ 0         bf16 [32768 n][256 j] ushort4 (64 MiB)
//   Gb @ 16777216  bf16 (64 MiB); later kernT bf16 [8][4096][512] (32 MiB)
//   V  @ 33554432  bf16 [32768][512] (32 MiB); first xt, later Pch
//   HF @ 41943040  bf16 [32768][512] (32 MiB)
// SERIAL ws, REQ = 134,217,728 B: G@0, V@16777216 (later kernT), xt/HF@25165824.
// d_out tail scratch (fl offset): wt bf16 @ +8388608 ([vf;vb;hf;hb][512k]),
//   cw2b @ +9437184, cb2 @ +9568256, wq fp8 @ +9568768.
// ---------------------------------------------------------------------------

typedef __hip_bfloat16 bf16;
typedef short short8 __attribute__((ext_vector_type(8)));
typedef float f4 __attribute__((ext_vector_type(4)));
typedef int int4v __attribute__((ext_vector_type(4)));
typedef int int8v __attribute__((ext_vector_type(8)));

#define SCL8 0x7F7F7F7F   // e8m0 = 127 in every byte -> scale 1.0 everywhere

__device__ __forceinline__ unsigned short bfbits(float f) {
    bf16 h = __float2bfloat16(f);
    return *reinterpret_cast<unsigned short*>(&h);
}
__device__ __forceinline__ float bf2f(unsigned short u) {
    union { unsigned int i; float f; } x; x.i = ((unsigned int)u) << 16; return x.f;
}
__device__ __forceinline__ unsigned char f2fp8(float f) {
    __hip_fp8_e4m3 q(f);
    return *reinterpret_cast<unsigned char*>(&q);
}
__device__ __forceinline__ float sigm2(float x) {
    return __builtin_amdgcn_rcpf(1.0f + __builtin_amdgcn_exp2f(x * -1.44269504f));
}
__device__ __forceinline__ float tanh2(float x) {
    return 1.0f - 2.0f * __builtin_amdgcn_rcpf(1.0f + __builtin_amdgcn_exp2f(x * 2.88539008f));
}

// async global->LDS, 16B per lane; lds dest = wave-uniform base + lane*16.
#define GLD16(g, s) __builtin_amdgcn_global_load_lds(                          \
    (const __attribute__((address_space(1))) void*)(g),                        \
    (__attribute__((address_space(3))) void*)(s), 16, 0, 0)

// barrier that does NOT drain vmcnt: LDS ordering only.
#define LGKM_BARRIER() do {                                                    \
    asm volatile("s_waitcnt lgkmcnt(0)" ::: "memory");                         \
    __builtin_amdgcn_s_barrier();                                              \
} while (0)

// ---------------------------------------------------------------------------
// prep_weights: wt bf16 [4][1024 g][512 k]; cw2b [512][512]; cb2 [512];
//               wq e4m3 [4][1024 g][256 k].
// ---------------------------------------------------------------------------
__global__ __launch_bounds__(256)
void prep_weights(const float* __restrict__ w0, const float* __restrict__ w1,
                  const float* __restrict__ w2, const float* __restrict__ w3,
                  const float* __restrict__ cw, const float* __restrict__ cb,
                  const float* __restrict__ u0, const float* __restrict__ u1,
                  const float* __restrict__ u2, const float* __restrict__ u3,
                  bf16* __restrict__ wt, bf16* __restrict__ cw2b,
                  float* __restrict__ cb2, unsigned char* __restrict__ wq)
{
    int idx = blockIdx.x * 256 + threadIdx.x;
    if (idx < 2097152) {
        int mat = idx >> 19, rem = idx & 524287;
        const float* src = (mat == 0) ? w0 : (mat == 1) ? w1 : (mat == 2) ? w2 : w3;
        wt[idx] = __float2bfloat16(src[rem]);
    } else if (idx < 2097152 + 262144) {
        int r = idx - 2097152; int o = r >> 9, k = r & 511;
        cw2b[r] = __float2bfloat16((o < 484) ? cw[o * 512 + k] : 0.f);
    } else if (idx < 2097152 + 262144 + 512) {
        int o = idx - 2097152 - 262144;
        cb2[o] = (o < 484) ? cb[o] : 0.f;
    } else if (idx < 2097152 + 262144 + 512 + 1048576) {
        int r = idx - 2097152 - 262144 - 512;
        int mat = r >> 18, rem = r & 262143;
        const float* src = (mat == 0) ? u0 : (mat == 1) ? u1 : (mat == 2) ? u2 : u3;
        wq[r] = f2fp8(src[rem]);
    }
}

// ---------------------------------------------------------------------------
// xtrans: x [8][512][64][64] fp32 -> xt [b*4096 + h*64 + w][512 c] bf16.
// ---------------------------------------------------------------------------
__global__ __launch_bounds__(256)
void xtrans(const float* __restrict__ x, bf16* __restrict__ xt)
{
    __shared__ float T[64][65];
    const int tid = threadIdx.x;
    const int bid = blockIdx.x;
    const int b = bid >> 9, h = (bid >> 3) & 63, ct = bid & 7;
    const int c0 = ct << 6;
    const float* xp = x + ((long)(b * 512 + c0) * 64 + h) * 64;
    const int wv = tid >> 6, wl = tid & 63;
    #pragma unroll
    for (int r = 0; r < 16; ++r) {
        int ci = wv + (r << 2);
        T[ci][wl] = xp[(long)ci * 4096 + wl];
    }
    __syncthreads();
    const int wr = tid >> 2, cj = (tid & 3) << 4;
    bf16* op = xt + ((long)(b * 4096 + h * 64 + wr) * 512) + c0 + cj;
    short8 v0, v1;
    #pragma unroll
    for (int i = 0; i < 8; ++i) v0[i] = (short)bfbits(T[cj + i][wr]);
    #pragma unroll
    for (int i = 0; i < 8; ++i) v1[i] = (short)bfbits(T[cj + 8 + i][wr]);
    *(short8*)op = v0;
    *(short8*)(op + 8) = v1;
}

// ---------------------------------------------------------------------------
// gemm_lds: MFMA GEMM, T4 counted-vmcnt 2-deep staging.
// K=512, BK=64, tile 128x128, 256 thr. Prologue stages tiles 0,1. Per K-step:
// wait vmcnt(8) (tile kt landed; tile kt+1's 8 loads stay in flight) ->
// barrier -> MFMA(cur) -> barrier -> stage(kt+2 -> cur). Epilogue: vmcnt(0)
// only at kt=7. MODE 0 GATES (fused fwd+bwd, ushort4 out), MODE 2 FINAL.
// ---------------------------------------------------------------------------
template<int MODE>
__global__ __launch_bounds__(256)
void gemm_lds(const bf16* __restrict__ A, const bf16* __restrict__ W,
              const float* __restrict__ biasf, const float* __restrict__ biasb,
              void* __restrict__ outf, void* __restrict__ outb, int dironly)
{
    __shared__ alignas(16) char Abuf[2][16384];
    __shared__ alignas(16) char Bbuf[2][16384];
    const int tid = threadIdx.x;
    const int wv = tid >> 6, l = tid & 63;
    const int lm = l & 15, lg = l >> 4;
    const int wm = wv >> 1, wn = wv & 1;

    const int nx = gridDim.x;
    int bid = blockIdx.y * nx + blockIdx.x;
    const int cpx = (nx * gridDim.y) >> 3;
    bid = (bid & 7) * cpx + (bid >> 3);
    const int bx = bid % nx;
    const int n0 = (bid / nx) << 7;

    int dir = 0, jblk = 0, g0 = 0;
    const bf16* Wg = W;
    if (MODE == 0) {
        dir  = (dironly < 0) ? (bx >> 3) : dironly;
        jblk = (dironly < 0) ? (bx & 7) : bx;
    } else {
        g0 = bx << 7;
        if (MODE == 2) Wg += (long)(n0 >> 9) * 2097152;
    }

    f4 acc[4][4];
    #pragma unroll
    for (int mf = 0; mf < 4; ++mf)
        #pragma unroll
        for (int nf = 0; nf < 4; ++nf)
            acc[mf][nf] = (f4){0.f, 0.f, 0.f, 0.f};

    auto stage = [&](int kt, int pb) {
        const int k0 = kt << 6;
        #pragma unroll
        for (int i = 0; i < 4; ++i) {
            const int seg = (wv << 2) + i;
            const int L = (seg << 10) + l * 16;
            const int row = L >> 7;
            const int off = (L & 127) ^ ((row & 7) << 4);
            const bf16* ga = A + (long)(n0 + row) * 512 + k0 + (off >> 1);
            GLD16(ga, &Abuf[pb][seg << 10]);
        }
        #pragma unroll
        for (int i = 0; i < 4; ++i) {
            const int seg = (wv << 2) + i;
            const int L = (seg << 10) + l * 16;
            const int row = L >> 7;
            const int off = (L & 127) ^ ((row & 7) << 4);
            int wrow;
            if (MODE == 0) wrow = (dir << 10) + ((row >> 5) << 8) + jblk * 32 + (row & 31);
            else           wrow = g0 + row;
            const bf16* gb = Wg + (long)wrow * 512 + k0 + (off >> 1);
            GLD16(gb, &Bbuf[pb][seg << 10]);
        }
    };

    // prologue: 2-deep — tiles 0 and 1 both in flight (16 vmem ops/lane)
    stage(0, 0);
    stage(1, 1);

    int cur = 0;
    for (int kt = 0; kt < 8; ++kt) {
        // wait ONLY tile kt's 8 loads; tile kt+1's 8 stay in flight
        if (kt < 7) asm volatile("s_waitcnt vmcnt(8)" ::: "memory");
        else        asm volatile("s_waitcnt vmcnt(0)" ::: "memory");
        __builtin_amdgcn_s_barrier();           // tile cur visible block-wide

        #pragma unroll
        for (int kk = 0; kk < 2; ++kk) {
            short8 af[4], bq[4];
            #pragma unroll
            for (int mf = 0; mf < 4; ++mf) {
                const int row = wm * 64 + mf * 16 + lm;
                const int ad = (row << 7) + ((((kk << 6) + (lg << 4))) ^ ((row & 7) << 4));
                af[mf] = *(const short8*)&Abuf[cur][ad];
            }
            #pragma unroll
            for (int nf = 0; nf < 4; ++nf) {
                const int row = (MODE == 0) ? (nf * 32 + wn * 16 + lm)
                                            : (wn * 64 + nf * 16 + lm);
                const int ad = (row << 7) + ((((kk << 6) + (lg << 4))) ^ ((row & 7) << 4));
                bq[nf] = *(const short8*)&Bbuf[cur][ad];
            }
            #pragma unroll
            for (int mf = 0; mf < 4; ++mf)
                #pragma unroll
                for (int nf = 0; nf < 4; ++nf)
                    acc[mf][nf] = __builtin_amdgcn_mfma_f32_16x16x32_bf16(af[mf], bq[nf], acc[mf][nf], 0, 0, 0);
        }

        asm volatile("s_waitcnt lgkmcnt(0)" ::: "memory");
        __builtin_amdgcn_s_barrier();           // all waves done reading cur
        if (kt < 6) stage(kt + 2, cur);         // overwrite cur with tile kt+2
        cur ^= 1;
    }

    if (MODE == 0) {
        const float* bs = dir ? biasb : biasf;
        const int jglob = jblk * 32 + wn * 16 + lm;
        float bv[4];
        #pragma unroll
        for (int nf = 0; nf < 4; ++nf) bv[nf] = bs[nf * 256 + jglob];
        ushort4* Gd = (ushort4*)(dir ? outb : outf);
        #pragma unroll
        for (int mf = 0; mf < 4; ++mf) {
            #pragma unroll
            for (int r = 0; r < 4; ++r) {
                const int n = n0 + wm * 64 + mf * 16 + lg * 4 + r;
                ushort4 u;
                u.x = bfbits(acc[mf][0][r] + bv[0]);
                u.y = bfbits(acc[mf][1][r] + bv[1]);
                u.z = bfbits(acc[mf][2][r] + bv[2]);
                u.w = bfbits(acc[mf][3][r] + bv[3]);
                Gd[(long)n * 256 + jglob] = u;
            }
        }
    } else {
        float* o = (float*)outf;
        #pragma unroll
        for (int mf = 0; mf < 4; ++mf)
            #pragma unroll
            for (int r = 0; r < 4; ++r) {
                const int n = n0 + wm * 64 + mf * 16 + lg * 4 + r;
                #pragma unroll
                for (int nf = 0; nf < 4; ++nf)
                    o[(long)n * 4096 + g0 + wn * 64 + nf * 16 + lm] = acc[mf][nf][r];
            }
    }
}

// ---------------------------------------------------------------------------
// conv_sm: fused 1x1 conv + bias + row-softmax(o<484) -> kernT bf16 [n][512].
// (R12, unchanged.)
// ---------------------------------------------------------------------------
__global__ __launch_bounds__(512)
void conv_sm(const bf16* __restrict__ A, const bf16* __restrict__ W,
             const float* __restrict__ bias, bf16* __restrict__ KT)
{
    __shared__ alignas(16) char SMEM[83968];
    char* Ab = SMEM;
    char* Bb = SMEM + 16384;
    float (*red)[4] = (float(*)[4])(SMEM + 81920);

    const int tid = threadIdx.x;
    const int wv = tid >> 6, l = tid & 63;
    const int lm = l & 15, lg = l >> 4;
    const int wm = wv >> 2, wn = wv & 3;
    const int n0 = blockIdx.x << 7;

    f4 acc[4][8];
    #pragma unroll
    for (int mf = 0; mf < 4; ++mf)
        #pragma unroll
        for (int nf = 0; nf < 8; ++nf)
            acc[mf][nf] = (f4){0.f, 0.f, 0.f, 0.f};

    for (int kt = 0; kt < 8; ++kt) {
        const int k0 = kt << 6;
        #pragma unroll
        for (int i = 0; i < 2; ++i) {
            const int L = (i << 13) + tid * 16;
            const int row = L >> 7;
            const int off = (L & 127) ^ ((row & 7) << 4);
            GLD16(A + (long)(n0 + row) * 512 + k0 + (off >> 1),
                  Ab + (i << 13) + (wv << 10));
        }
        #pragma unroll
        for (int j = 0; j < 8; ++j) {
            const int L = (j << 13) + tid * 16;
            const int row = L >> 7;
            const int off = (L & 127) ^ ((row & 7) << 4);
            GLD16(W + (long)row * 512 + k0 + (off >> 1),
                  Bb + (j << 13) + (wv << 10));
        }
        __syncthreads();
        #pragma unroll
        for (int kk = 0; kk < 2; ++kk) {
            short8 af[4], bq[8];
            #pragma unroll
            for (int mf = 0; mf < 4; ++mf) {
                const int row = wm * 64 + mf * 16 + lm;
                const int ad = (row << 7) + ((((kk << 6) + (lg << 4))) ^ ((row & 7) << 4));
                af[mf] = *(const short8*)&Ab[ad];
            }
            #pragma unroll
            for (int nf = 0; nf < 8; ++nf) {
                const int row = wn * 128 + nf * 16 + lm;
                const int ad = (row << 7) + ((((kk << 6) + (lg << 4))) ^ ((row & 7) << 4));
                bq[nf] = *(const short8*)&Bb[ad];
            }
            #pragma unroll
            for (int mf = 0; mf < 4; ++mf)
                #pragma unroll
                for (int nf = 0; nf < 8; ++nf)
                    acc[mf][nf] = __builtin_amdgcn_mfma_f32_16x16x32_bf16(af[mf], bq[nf], acc[mf][nf], 0, 0, 0);
        }
        __syncthreads();
    }

    float bv[8];
    bool alive[8];
    #pragma unroll
    for (int nf = 0; nf < 8; ++nf) {
        const int col = wn * 128 + nf * 16 + lm;
        bv[nf] = bias[col];
        alive[nf] = (col < 484);
    }

    #pragma unroll
    for (int mf = 0; mf < 4; ++mf) {
        #pragma unroll
        for (int r = 0; r < 4; ++r) {
            float m = -3.4e38f;
            #pragma unroll
            for (int nf = 0; nf < 8; ++nf) {
                float v = acc[mf][nf][r] + bv[nf];
                if (alive[nf]) m = fmaxf(m, v);
            }
            m = fmaxf(m, __shfl_xor(m, 1));
            m = fmaxf(m, __shfl_xor(m, 2));
            m = fmaxf(m, __shfl_xor(m, 4));
            m = fmaxf(m, __shfl_xor(m, 8));
            if (lm == 0) red[wm * 64 + mf * 16 + lg * 4 + r][wn] = m;
        }
    }
    __syncthreads();
    float mxv[4][4];
    #pragma unroll
    for (int mf = 0; mf < 4; ++mf)
        #pragma unroll
        for (int r = 0; r < 4; ++r) {
            const int row = wm * 64 + mf * 16 + lg * 4 + r;
            mxv[mf][r] = fmaxf(fmaxf(red[row][0], red[row][1]),
                               fmaxf(red[row][2], red[row][3]));
        }
    __syncthreads();
    #pragma unroll
    for (int mf = 0; mf < 4; ++mf) {
        #pragma unroll
        for (int r = 0; r < 4; ++r) {
            float s = 0.f;
            #pragma unroll
            for (int nf = 0; nf < 8; ++nf) {
                float v = acc[mf][nf][r] + bv[nf];
                float e = alive[nf]
                    ? __builtin_amdgcn_exp2f((v - mxv[mf][r]) * 1.44269504f) : 0.f;
                acc[mf][nf][r] = e;
                s += e;
            }
            s += __shfl_xor(s, 1);
            s += __shfl_xor(s, 2);
            s += __shfl_xor(s, 4);
            s += __shfl_xor(s, 8);
            if (lm == 0) red[wm * 64 + mf * 16 + lg * 4 + r][wn] = s;
        }
    }
    __syncthreads();
    float invv[4][4];
    #pragma unroll
    for (int mf = 0; mf < 4; ++mf)
        #pragma unroll
        for (int r = 0; r < 4; ++r) {
            const int row = wm * 64 + mf * 16 + lg * 4 + r;
            invv[mf][r] = __builtin_amdgcn_rcpf(red[row][0] + red[row][1] +
                                                red[row][2] + red[row][3]);
        }

    unsigned short* TB = (unsigned short*)Bb;
    unsigned short* KTu = (unsigned short*)KT;
    #pragma unroll
    for (int hm = 0; hm < 2; ++hm) {
        __syncthreads();
        if (wm == hm) {
            #pragma unroll
            for (int mf = 0; mf < 4; ++mf)
                #pragma unroll
                for (int r = 0; r < 4; ++r) {
                    const int rr = mf * 16 + lg * 4 + r;
                    #pragma unroll
                    for (int nf = 0; nf < 8; ++nf)
                        TB[rr * 512 + wn * 128 + nf * 16 + lm] =
                            bfbits(acc[mf][nf][r] * invv[mf][r]);
                }
        }
        __syncthreads();
        #pragma unroll
        for (int s = 0; s < 8; ++s) {
            const int L = (s << 13) + tid * 16;
            const int rr = L >> 10;
            const int cc = (L & 1023) >> 1;
            *(short8*)(KTu + (long)(n0 + hm * 64 + rr) * 512 + cc) =
                *(const short8*)((const char*)TB + L);
        }
    }
}

// ---------------------------------------------------------------------------
// lstm4s: spread-row MX-fp8 MFMA recurrence (16x16x128, unit scales). R11/R12.
// ---------------------------------------------------------------------------
__global__ __launch_bounds__(1024, 4)
void lstm4s(const bf16* __restrict__ Gf, const bf16* __restrict__ Gb,
            const unsigned char* __restrict__ Wqf, const unsigned char* __restrict__ Wqb,
            bf16* __restrict__ Out, int dir_force)
{
    __shared__ char ldspad[83968];              // 82 KB occupancy limiter
    __shared__ unsigned char hbuf[2][4][256];   // 2 KB fp8 h, col-rotated
    const int tid = threadIdx.x;
    const int wv = tid >> 6, l = tid & 63;
    const int lm = l & 15, lg = l >> 4;
    const int j_c = wv * 16 + lm;
    const int s_a = lm >> 2;

    int dir, sblk;
    if (dir_force >= 0) { dir = dir_force; sblk = blockIdx.x; }
    else               { dir = blockIdx.x >> 7; sblk = blockIdx.x & 127; }
    if (dir_force == -9999) ((volatile char*)ldspad)[tid] = 1;

    const bf16* G = dir ? Gb : Gf;
    const unsigned char* WQ = dir ? Wqb : Wqf;
    const int s0 = sblk << 2;

    int8v wfrag[4][2];
    #pragma unroll
    for (int q = 0; q < 4; ++q) {
        const unsigned char* wr = WQ + (long)(q * 256 + wv * 16 + lm) * 256 + lg * 32;
        #pragma unroll
        for (int kt = 0; kt < 2; ++kt) {
            int4v lo = *(const int4v*)(wr + kt * 128);
            int4v hi = *(const int4v*)(wr + kt * 128 + 16);
            int8v w;
            w[0] = lo[0]; w[1] = lo[1]; w[2] = lo[2]; w[3] = lo[3];
            w[4] = hi[0]; w[5] = hi[1]; w[6] = hi[2]; w[7] = hi[3];
            wfrag[q][kt] = w;
        }
    }

    if (tid < 256) ((unsigned long*)hbuf)[tid] = 0ul;

    float cst = 0.f;
    const ushort4* G4 = (const ushort4*)G;
    const int sg = s0 + lg;
    const long gb0 = (long)sg * 16384 + j_c;
    const long ob0 = ((long)((s0 >> 6) * 4096 + (s0 & 63) + lg)) * 512 + (dir << 8) + j_c;
    unsigned short* Ou = (unsigned short*)Out;

    ushort4 uA, uB;
    {
        int t0 = dir ? 63 : 0, t1 = dir ? 62 : 1;
        uA = G4[gb0 + (long)t0 * 256];
        uB = G4[gb0 + (long)t1 * 256];
    }
    LGKM_BARRIER();

#define LSTM_STEP(SP, UREG, RB, WB)                                             \
    {                                                                           \
        const int t_ = dir ? (63 - (SP)) : (SP);                                \
        int8v af0, af1;                                                         \
        {                                                                       \
            const unsigned char* hb = &hbuf[RB][s_a][0];                        \
            const int c0 = ((lg << 5) + (s_a << 5)) & 255;                      \
            const int c1 = (128 + (lg << 5) + (s_a << 5)) & 255;                \
            int4v a0 = *(const int4v*)(hb + c0);                                \
            int4v a1 = *(const int4v*)(hb + c0 + 16);                           \
            int4v b0 = *(const int4v*)(hb + c1);                                \
            int4v b1 = *(const int4v*)(hb + c1 + 16);                           \
            af0[0]=a0[0]; af0[1]=a0[1]; af0[2]=a0[2]; af0[3]=a0[3];             \
            af0[4]=a1[0]; af0[5]=a1[1]; af0[6]=a1[2]; af0[7]=a1[3];             \
            af1[0]=b0[0]; af1[1]=b0[1]; af1[2]=b0[2]; af1[3]=b0[3];             \
            af1[4]=b1[0]; af1[5]=b1[1]; af1[6]=b1[2]; af1[7]=b1[3];             \
        }                                                                       \
        f4 ac0 = {0.f,0.f,0.f,0.f}, ac1 = {0.f,0.f,0.f,0.f};                    \
        f4 ac2 = {0.f,0.f,0.f,0.f}, ac3 = {0.f,0.f,0.f,0.f};                    \
        ac0[0] = bf2f(UREG.x); ac1[0] = bf2f(UREG.y);                           \
        ac2[0] = bf2f(UREG.z); ac3[0] = bf2f(UREG.w);                           \
        {                                                                       \
            int sp2 = (SP) + 2; if (sp2 > 63) sp2 = 63;                         \
            int tp = dir ? (63 - sp2) : sp2;                                    \
            UREG = G4[gb0 + (long)tp * 256];                                    \
        }                                                                       \
        ac0 = __builtin_amdgcn_mfma_scale_f32_16x16x128_f8f6f4(af0, wfrag[0][0], ac0, 0, 0, 0, SCL8, 0, SCL8); \
        ac1 = __builtin_amdgcn_mfma_scale_f32_16x16x128_f8f6f4(af0, wfrag[1][0], ac1, 0, 0, 0, SCL8, 0, SCL8); \
        ac2 = __builtin_amdgcn_mfma_scale_f32_16x16x128_f8f6f4(af0, wfrag[2][0], ac2, 0, 0, 0, SCL8, 0, SCL8); \
        ac3 = __builtin_amdgcn_mfma_scale_f32_16x16x128_f8f6f4(af0, wfrag[3][0], ac3, 0, 0, 0, SCL8, 0, SCL8); \
        ac0 = __builtin_amdgcn_mfma_scale_f32_16x16x128_f8f6f4(af1, wfrag[0][1], ac0, 0, 0, 0, SCL8, 0, SCL8); \
        ac1 = __builtin_amdgcn_mfma_scale_f32_16x16x128_f8f6f4(af1, wfrag[1][1], ac1, 0, 0, 0, SCL8, 0, SCL8); \
        ac2 = __builtin_amdgcn_mfma_scale_f32_16x16x128_f8f6f4(af1, wfrag[2][1], ac2, 0, 0, 0, SCL8, 0, SCL8); \
        ac3 = __builtin_amdgcn_mfma_scale_f32_16x16x128_f8f6f4(af1, wfrag[3][1], ac3, 0, 0, 0, SCL8, 0, SCL8); \
        {                                                                       \
            float ii = sigm2(ac0[0]);                                           \
            float ff = sigm2(ac1[0]);                                           \
            float gc = tanh2(ac2[0]);                                           \
            float oo = sigm2(ac3[0]);                                           \
            float c  = ff * cst + ii * gc;                                      \
            cst = c;                                                            \
            float h_ = oo * tanh2(c);                                           \
            hbuf[WB][lg][(j_c + (lg << 5)) & 255] = f2fp8(h_);                  \
            Ou[ob0 + (long)t_ * 32768] = bfbits(h_);                            \
        }                                                                       \
        LGKM_BARRIER();                                                         \
    }

    for (int sp = 0; sp < 64; sp += 2) {
        LSTM_STEP(sp,     uA, 0, 1)
        LSTM_STEP(sp + 1, uB, 1, 0)
    }
#undef LSTM_STEP
}

// ---------------------------------------------------------------------------
// gather_patch: Pch[b*512+c][o] = bf16(x[b, c, 3*(o/22), 3*(o%22)]), 0 o>=484.
// ---------------------------------------------------------------------------
__global__ __launch_bounds__(256)
void gather_patch(const float* __restrict__ x, bf16* __restrict__ Pch)
{
    int idx = blockIdx.x * 256 + threadIdx.x;
    if (idx >= 2097152) return;
    int o = idx & 511, c = (idx >> 9) & 511, b = idx >> 18;
    float v = 0.f;
    if (o < 484) {
        int i = o / 22, jj = o - i * 22;
        v = x[(long)b * 2097152 + (long)c * 4096 + i * 192 + jj * 3];
    }
    Pch[idx] = __float2bfloat16(v);
}

// ---------------------------------------------------------------------------
extern "C" void kernel_launch(void* const* d_in, const int* in_sizes, int n_in,
                              void* d_out, int out_size, void* d_ws, size_t ws_size,
                              hipStream_t stream)
{
    const float* x        = (const float*)d_in[0];
    const float* v_wih_f  = (const float*)d_in[1];
    const float* v_whh_f  = (const float*)d_in[2];
    const float* v_b_f    = (const float*)d_in[3];
    const float* v_wih_b  = (const float*)d_in[4];
    const float* v_whh_b  = (const float*)d_in[5];
    const float* v_b_b    = (const float*)d_in[6];
    const float* h_wih_f  = (const float*)d_in[7];
    const float* h_whh_f  = (const float*)d_in[8];
    const float* h_b_f    = (const float*)d_in[9];
    const float* h_wih_b  = (const float*)d_in[10];
    const float* h_whh_b  = (const float*)d_in[11];
    const float* h_b_b    = (const float*)d_in[12];
    const float* conv_w   = (const float*)d_in[13];
    const float* conv_b   = (const float*)d_in[14];

    const size_t REQ_FUSED  = 50331648UL * 4UL;   // 201,326,592 B
    const size_t REQ_SERIAL = 33554432UL * 4UL;   // 134,217,728 B
    if (ws_size < REQ_SERIAL) return;
    const bool fused = (ws_size >= REQ_FUSED);

    float* wsf = (float*)d_ws;
    float* out = (float*)d_out;

    // d_out tail scratch (dead before final gemm)
    bf16*          wt   = (bf16*)(out + 8388608);
    bf16*          cw2b = (bf16*)(out + 9437184);
    float*         cb2  = out + 9568256;
    unsigned char* wq   = (unsigned char*)(out + 9568768);

    prep_weights<<<13314, 256, 0, stream>>>(v_wih_f, v_wih_b, h_wih_f, h_wih_b,
                                            conv_w, conv_b,
                                            v_whh_f, v_whh_b, h_whh_f, h_whh_b,
                                            wt, cw2b, cb2, wq);
    bf16* wt_v = wt;                 // [vf;vb] 2048 rows
    bf16* wt_h = wt + 1048576;       // [hf;hb] 2048 rows
    unsigned char* wq_vf = wq;
    unsigned char* wq_vb = wq + 262144;
    unsigned char* wq_hf = wq + 524288;
    unsigned char* wq_hb = wq + 786432;

    dim3 gG(16, 256);   // fused gate GEMM: 2 dirs x 8 jblks, 256 row-tiles
    dim3 gGs(8, 256);   // serial gate GEMM: one dir
    dim3 gF(32, 32);    // final: 4096 cols, 4096 rows

    if (fused) {
        bf16*  Gf    = (bf16*)d_ws;
        bf16*  Gb    = (bf16*)(wsf + 16777216);
        bf16*  V     = (bf16*)(wsf + 33554432);
        bf16*  HF    = (bf16*)(wsf + 41943040);
        bf16*  xt    = V;                      // dead after vertical GEMM
        bf16*  kernT = Gb;                     // aliases Gb
        bf16*  Pch   = V;                      // aliases V

        xtrans<<<4096, 256, 0, stream>>>(x, xt);
        gemm_lds<0><<<gG, 256, 0, stream>>>(xt, wt_v, v_b_f, v_b_b, Gf, Gb, -1);
        lstm4s<<<256, 1024, 0, stream>>>(Gf, Gb, wq_vf, wq_vb, V, -1);

        gemm_lds<0><<<gG, 256, 0, stream>>>(V, wt_h, h_b_f, h_b_b, Gf, Gb, -1);
        lstm4s<<<256, 1024, 0, stream>>>(Gf, Gb, wq_hf, wq_hb, HF, -1);

        conv_sm<<<256, 512, 0, stream>>>(HF, cw2b, cb2, kernT);
        gather_patch<<<8192, 256, 0, stream>>>(x, Pch);
        gemm_lds<2><<<gF, 256, 0, stream>>>(Pch, kernT, nullptr, nullptr, out, nullptr, 0);
    } else {
        bf16*  G     = (bf16*)d_ws;
        bf16*  V     = (bf16*)(wsf + 16777216);
        bf16*  xt    = (bf16*)(wsf + 25165824);
        bf16*  HF    = xt;
        bf16*  kernT = V;
        bf16*  Pch   = (bf16*)d_ws;            // aliases G (dead after lstm)

        xtrans<<<4096, 256, 0, stream>>>(x, xt);
        gemm_lds<0><<<gGs, 256, 0, stream>>>(xt, wt_v, v_b_f, v_b_b, G, G, 0);
        lstm4s<<<128, 1024, 0, stream>>>(G, G, wq_vf, wq_vf, V, 0);
        gemm_lds<0><<<gGs, 256, 0, stream>>>(xt, wt_v, v_b_f, v_b_b, G, G, 1);
        lstm4s<<<128, 1024, 0, stream>>>(G, G, wq_vb, wq_vb, V, 1);

        gemm_lds<0><<<gGs, 256, 0, stream>>>(V, wt_h, h_b_f, h_b_b, G, G, 0);
        lstm4s<<<128, 1024, 0, stream>>>(G, G, wq_hf, wq_hf, HF, 0);
        gemm_lds<0><<<gGs, 256, 0, stream>>>(V, wt_h, h_b_f, h_b_b, G, G, 1);
        lstm4s<<<128, 1024, 0, stream>>>(G, G, wq_hb, wq_hb, HF, 1);

        conv_sm<<<256, 512, 0, stream>>>(HF, cw2b, cb2, kernT);
        gather_patch<<<8192, 256, 0, stream>>>(x, Pch);
        gemm_lds<2><<<gF, 256, 0, stream>>>(Pch, kernT, nullptr, nullptr, out, nullptr, 0);
    }
}